// Round 17
// baseline (159.295 us; speedup 1.0000x reference)
//
#include <hip/hip_runtime.h>
#include <hip/hip_bf16.h>

typedef short bf8 __attribute__((ext_vector_type(8)));   // 8 bf16 (4 VGPRs)
typedef short bf4 __attribute__((ext_vector_type(4)));   // 4 bf16 (8 B)
typedef float f4 __attribute__((ext_vector_type(4)));
typedef const __attribute__((address_space(1))) void* gvp;
typedef __attribute__((address_space(3))) void* lvp;

#define S_LEN 4096
#define H_DIM 1024
#define D_DIM 512
#define B_DIM 16
#define OUT_BASE ((size_t)B_DIM * S_LEN * H_DIM)

// float -> bf16 bits, round-to-nearest-even
static __device__ __forceinline__ unsigned short f2bf(float f) {
    union { float f; unsigned int u; } c; c.f = f;
    unsigned int u = c.u;
    return (unsigned short)((u + 0x7FFFu + ((u >> 16) & 1u)) >> 16);
}

// cW1 [K=1024][N=512] f32 -> wT[n][chunk 0..31][slot 0..3] bf16 (pitch 2048 B),
// PRE-SWIZZLED: slot sl holds k-slot j = sl ^ ((n>>1)&3). GEMM's linear global_load_lds
// + swizzled ds_read (slot = lg ^ ((la>>1)&3)) recovers k-slot lg; 2-way-bank (free).
__global__ __launch_bounds__(256) void prep_transpose(const float* __restrict__ cW1,
                                                      unsigned short* __restrict__ wT) {
    __shared__ float tile[64][68];
    const int kt = blockIdx.x >> 3;   // 16 tiles of 64 k
    const int nt = blockIdx.x & 7;    // 8 tiles of 64 n
    const int tr = threadIdx.x >> 4;
    const int tc = threadIdx.x & 15;
#pragma unroll
    for (int i = 0; i < 4; ++i) {
        const f4 v = *(const f4*)(cW1 + (size_t)(kt * 64 + i * 16 + tr) * D_DIM + nt * 64 + tc * 4);
        tile[i * 16 + tr][tc * 4 + 0] = v.x;
        tile[i * 16 + tr][tc * 4 + 1] = v.y;
        tile[i * 16 + tr][tc * 4 + 2] = v.z;
        tile[i * 16 + tr][tc * 4 + 3] = v.w;
    }
    __syncthreads();
    const int n_local = threadIdx.x & 63;
    const int q = threadIdx.x >> 6;        // slot 0..3
    const int n = nt * 64 + n_local;
    const int j = q ^ ((n >> 1) & 3);      // data k-slot stored at slot q
    char* wTb = (char*)wT;
#pragma unroll
    for (int c_local = 0; c_local < 2; ++c_local) {   // two 32-k chunks per 64k tile
        const int k0 = c_local * 32 + j * 8;
        bf8 pk;
#pragma unroll
        for (int i = 0; i < 8; ++i) pk[i] = (short)f2bf(tile[k0 + i][n_local]);
        *(bf8*)(wTb + (size_t)n * 2048 + (kt * 2 + c_local) * 64 + q * 16) = pk;
    }
}

// Fused stream+GEMM, 3 gangs/CU. M=64 (one b, 64 s) x N=256 (one D-half), BK=32,
// 32 chunks, 8 waves (2M x 4N), acc[2][4]=32 AGPR + ~52 VGPR = 84 regs <= 85 ->
// 6 waves/SIMD; LDS 40 KB (B dbuf 32 KB + A dbuf 8 KB) -> 3 blocks/CU (reg-capped).
// Depth-1 B is safe (B from L2, ~150 ns << 2 us period). Role-split copy-out
// (block nhalf stores chunks ck>>4==nhalf: each out element once); nt dense stores;
// XCD pair-swizzle co-locates the two halves of a slab. Counted tails: vmcnt(2)
// when this iter stored ([B x2, st, glA]), vmcnt(1) when not; 0 only at ck=30.
__global__ __launch_bounds__(512, 6) void comp_gemm_kernel(
    const float* __restrict__ states,
    const unsigned short* __restrict__ wT,
    const float* __restrict__ cb1,
    const float* __restrict__ cW2,
    float* __restrict__ out,
    float* __restrict__ part_ws) {
    __shared__ alignas(16) char lds[40960];   // B [2][256][64] @0 ; A [2][64][64] @32768
    char* ldsB = lds;
    char* ldsA = lds + 32768;

    const int t = threadIdx.x;
    const int lane = t & 63;
    const int wv = t >> 6;                // 0..7
    const int wm = wv >> 2;               // 0..1 : rows [wm*32, +32)
    const int wn = wv & 3;                // 0..3 : cols [wn*64, +64)
    const int la = lane & 15;
    const int lg = lane >> 4;

    // XCD pair-swizzle: consecutive logical ids land on the same XCD
    const int bid = blockIdx.x;
    const int bidL = (bid & 7) * 256 + (bid >> 3);
    const int b = bidL >> 7;              // 16 b
    const int rem = bidL & 127;
    const int s0 = (rem >> 1) * 64;       // 64 s-tiles of 64
    const int nhalf = rem & 1;            // 2 N-halves
    const int n0 = nhalf * 256;

    // ---- A staging / fused copy-out: (row = t>>3, kq = t&7), one f4 = 16 B/thread;
    // 8 threads/row cover 128 B contiguous -> wave store = 8 rows x 128 B DENSE ----
    const int arow = t >> 3;
    const int kq = t & 7;
    const size_t abase = ((size_t)b * S_LEN + s0 + arow) * H_DIM + kq * 4;
    const float* srcA = states + abase;
    float* dstO = out + abase;
    const int ax = (arow & 3) ^ ((arow >> 2) & 3);            // A slot swizzle X(row)
    char* dstA = ldsA + arow * 64 + ((((kq >> 1) ^ ax) & 3) * 16 + (kq & 1) * 8);

    // ---- B staging: 2 x global_load_lds(16B/lane)/chunk; linear dest, swizzled src ----
    const char* srcB = (const char*)wT + (size_t)(n0 + (t >> 2)) * 2048 + (t & 3) * 16;
    char* dstB = ldsB + t * 16;

    // ---- fragment read bases (2-way bank, free) ----
    const char* brd = ldsB + (wn * 64 + la) * 64 + ((lg ^ ((la >> 1) & 3)) * 16);
    const char* ard = ldsA + (wm * 32 + la) * 64 + ((lg ^ (la & 3) ^ ((la >> 2) & 3)) * 16);

    f4 acc[2][4];
#pragma unroll
    for (int a = 0; a < 2; ++a)
#pragma unroll
        for (int c = 0; c < 4; ++c) acc[a][c] = f4{0.f, 0.f, 0.f, 0.f};

    auto issueB = [&](int bufi, int ck_) {
#pragma unroll
        for (int i = 0; i < 2; ++i)
            __builtin_amdgcn_global_load_lds((gvp)(srcB + (size_t)i * 128 * 2048 + ck_ * 64),
                                             (lvp)(dstB + bufi * 16384 + i * 8192), 16, 0, 0);
    };
    auto writeA = [&](int bufa, const f4 a) {
        bf4 p;
        p[0] = (short)f2bf(a.x); p[1] = (short)f2bf(a.y);
        p[2] = (short)f2bf(a.z); p[3] = (short)f2bf(a.w);
        *(bf4*)(dstA + bufa * 4096) = p;
    };
    auto storeO = [&](int ck_, const f4 a) {   // nt, per-instruction dense
        __builtin_nontemporal_store(a, (f4*)(dstO + ck_ * 32));
    };

    // ---- prologue: [glA0, B0 x2, (writeA waits glA0), st0?, glA1] ----
    f4 qa = *(const f4*)(srcA);
    issueB(0, 0);
    writeA(0, qa);                       // auto-wait retires glA0, leaves B0 x2
    if (nhalf == 0) storeO(0, qa);       // chunk 0 belongs to nhalf 0
    f4 qn = *(const f4*)(srcA + 32);
    if (nhalf == 0) { asm volatile("s_waitcnt vmcnt(2) lgkmcnt(0)" ::: "memory"); }
    else            { asm volatile("s_waitcnt vmcnt(1) lgkmcnt(0)" ::: "memory"); }
    __builtin_amdgcn_sched_barrier(0);
    __builtin_amdgcn_s_barrier();
    __builtin_amdgcn_sched_barrier(0);
    qa = qn;

#pragma unroll 1
    for (int ck = 0; ck < 32; ++ck) {
        const int buf = ck & 1;
        bool stored = false;
        if (ck < 31) {
            issueB(buf ^ 1, ck + 1);                    // B(ck+1) -> other buffer, stays flying
            writeA(buf ^ 1, qa);                        // auto-wait retires [st_old?, glA(ck+1)]
            stored = ((ck + 1) >> 4) == nhalf;
            if (stored) storeO(ck + 1, qa);             // role-split copy-out
            if (ck < 30) qn = *(const f4*)(srcA + (ck + 2) * 32);
            __builtin_amdgcn_sched_barrier(0);
        }
        // ---- compute chunk ck: A from ldsA[buf], B from ldsB[buf] ----
        bf8 af[2];
#pragma unroll
        for (int fr = 0; fr < 2; ++fr)
            af[fr] = *(const bf8*)(ard + buf * 4096 + fr * 1024);
#pragma unroll
        for (int fc = 0; fc < 4; ++fc) {
            const bf8 bv = *(const bf8*)(brd + buf * 16384 + fc * 1024);
#pragma unroll
            for (int fr = 0; fr < 2; ++fr)
                acc[fr][fc] = __builtin_amdgcn_mfma_f32_16x16x32_bf16(af[fr], bv, acc[fr][fc], 0, 0, 0);
        }
        if (ck < 31) {
            // tail: retire B(ck+1) x2 exactly. queue (stored): [B x2, st, glA] -> vmcnt(2)
            //                                   (no store):   [B x2, glA]      -> vmcnt(1)
            if (ck < 30) {
                if (stored) { asm volatile("s_waitcnt vmcnt(2) lgkmcnt(0)" ::: "memory"); }
                else        { asm volatile("s_waitcnt vmcnt(1) lgkmcnt(0)" ::: "memory"); }
            } else {
                asm volatile("s_waitcnt vmcnt(0) lgkmcnt(0)" ::: "memory");   // one-time drain
            }
            __builtin_amdgcn_sched_barrier(0);
            __builtin_amdgcn_s_barrier();
            __builtin_amdgcn_sched_barrier(0);
            if (ck < 30) qa = qn;
        }
    }

    // ---- epilogue: relu + dot(cW2-half) -> raw half-logit per (b,s) ----
    float w2v[4], b1v[4];
#pragma unroll
    for (int fc = 0; fc < 4; ++fc) {
        const int d = n0 + wn * 64 + fc * 16 + la;
        w2v[fc] = cW2[d];
        b1v[fc] = cb1[d];
    }
    float* part = (float*)ldsA;   // [64 rows][4 wn] overlays A-buf0 (iter31 read A-buf1)
#pragma unroll
    for (int fr = 0; fr < 2; ++fr) {
#pragma unroll
        for (int rg = 0; rg < 4; ++rg) {
            float p = 0.f;
#pragma unroll
            for (int fc = 0; fc < 4; ++fc)
                p += fmaxf(acc[fr][fc][rg] + b1v[fc], 0.f) * w2v[fc];
#pragma unroll
            for (int off = 1; off < 16; off <<= 1)
                p += __shfl_xor(p, off, 64);      // sum over 16 lane-columns (n)
            if (la == 0) part[(wm * 32 + fr * 16 + lg * 4 + rg) * 4 + wn] = p;
        }
    }
    __syncthreads();
    if (t < 64) {
        const float sum = part[t * 4 + 0] + part[t * 4 + 1] + part[t * 4 + 2] + part[t * 4 + 3];
        __builtin_nontemporal_store(
            sum, part_ws + ((size_t)(nhalf * B_DIM + b)) * S_LEN + s0 + t);
    }
}

// comp_mean[s] = (1/16) sum_b sigmoid(cb2 + half0[b][s] + half1[b][s]);
// steps_used ≡ 1 (rb<=128-t can never make trunc(rb/(S-t+1))>=2; negative rb clips
// to 1); rb_final = 128-4096 = -3968.
__global__ __launch_bounds__(256) void reduce_comp(const float* __restrict__ part_ws,
                                                   const float* __restrict__ cb2,
                                                   float* __restrict__ out) {
    const int s = blockIdx.x * 256 + threadIdx.x;
    const float c2 = cb2[0];
    float sum = 0.f;
#pragma unroll
    for (int b = 0; b < B_DIM; ++b) {
        const float l = c2 + part_ws[(size_t)b * S_LEN + s]
                           + part_ws[((size_t)B_DIM + b) * S_LEN + s];
        sum += 1.f / (1.f + __expf(-l));
    }
    out[OUT_BASE + S_LEN + s] = sum * (1.f / 16.f);   // comp_mean
    out[OUT_BASE + s] = 1.0f;                          // steps_used
    if (s == 0) out[OUT_BASE + 2 * S_LEN] = -3968.0f;  // rb_final.mean()
}

extern "C" void kernel_launch(void* const* d_in, const int* in_sizes, int n_in,
                              void* d_out, int out_size, void* d_ws, size_t ws_size,
                              hipStream_t stream) {
    const float* states = (const float*)d_in[0];
    const float* cW1 = (const float*)d_in[5];
    const float* cb1 = (const float*)d_in[6];
    const float* cW2 = (const float*)d_in[7];
    const float* cb2 = (const float*)d_in[8];
    float* out = (float*)d_out;
    unsigned short* wT = (unsigned short*)d_ws;                 // 1 MB bf16, pre-swizzled
    float* part_ws = (float*)((char*)d_ws + (size_t)D_DIM * H_DIM * 2);  // 512 KB [2][16][4096]

    hipLaunchKernelGGL(prep_transpose, dim3(128), dim3(256), 0, stream, cW1, wT);
    hipLaunchKernelGGL(comp_gemm_kernel, dim3(2048), dim3(512), 0, stream,
                       states, wT, cb1, cW2, out, part_ws);
    hipLaunchKernelGGL(reduce_comp, dim3(16), dim3(256), 0, stream, part_ws, cb2, out);
}

// Round 18
// 154.555 us; speedup vs baseline: 1.0307x; 1.0307x over previous
//
#include <hip/hip_runtime.h>
#include <hip/hip_bf16.h>

typedef short bf8 __attribute__((ext_vector_type(8)));   // 8 bf16 (4 VGPRs)
typedef short bf4 __attribute__((ext_vector_type(4)));   // 4 bf16 (8 B)
typedef float f4 __attribute__((ext_vector_type(4)));
typedef const __attribute__((address_space(1))) void* gvp;
typedef __attribute__((address_space(3))) void* lvp;

#define S_LEN 4096
#define H_DIM 1024
#define D_DIM 512
#define B_DIM 16
#define OUT_BASE ((size_t)B_DIM * S_LEN * H_DIM)

// float -> bf16 bits, round-to-nearest-even
static __device__ __forceinline__ unsigned short f2bf(float f) {
    union { float f; unsigned int u; } c; c.f = f;
    unsigned int u = c.u;
    return (unsigned short)((u + 0x7FFFu + ((u >> 16) & 1u)) >> 16);
}

// cW1 [K=1024][N=512] f32 -> wT[n][chunk 0..31][slot 0..3] bf16 (pitch 2048 B),
// PRE-SWIZZLED: slot sl holds k-slot j = sl ^ ((n>>1)&3). GEMM's linear global_load_lds
// + swizzled ds_read (slot = lg ^ ((la>>1)&3)) recovers k-slot lg; 2-way-bank (free).
__global__ __launch_bounds__(256) void prep_transpose(const float* __restrict__ cW1,
                                                      unsigned short* __restrict__ wT) {
    __shared__ float tile[64][68];
    const int kt = blockIdx.x >> 3;   // 16 tiles of 64 k
    const int nt = blockIdx.x & 7;    // 8 tiles of 64 n
    const int tr = threadIdx.x >> 4;
    const int tc = threadIdx.x & 15;
#pragma unroll
    for (int i = 0; i < 4; ++i) {
        const f4 v = *(const f4*)(cW1 + (size_t)(kt * 64 + i * 16 + tr) * D_DIM + nt * 64 + tc * 4);
        tile[i * 16 + tr][tc * 4 + 0] = v.x;
        tile[i * 16 + tr][tc * 4 + 1] = v.y;
        tile[i * 16 + tr][tc * 4 + 2] = v.z;
        tile[i * 16 + tr][tc * 4 + 3] = v.w;
    }
    __syncthreads();
    const int n_local = threadIdx.x & 63;
    const int q = threadIdx.x >> 6;        // slot 0..3
    const int n = nt * 64 + n_local;
    const int j = q ^ ((n >> 1) & 3);      // data k-slot stored at slot q
    char* wTb = (char*)wT;
#pragma unroll
    for (int c_local = 0; c_local < 2; ++c_local) {   // two 32-k chunks per 64k tile
        const int k0 = c_local * 32 + j * 8;
        bf8 pk;
#pragma unroll
        for (int i = 0; i < 8; ++i) pk[i] = (short)f2bf(tile[k0 + i][n_local]);
        *(bf8*)(wTb + (size_t)n * 2048 + (kt * 2 + c_local) * 64 + q * 16) = pk;
    }
}

// Fused stream+GEMM (R16 geometry verbatim; schedule edit only).
// M=128 (one b, 128 s) x N=256 (one D-half), BK=32, 32 chunks, 8 waves (2M x 4N),
// acc[4][4]=64 AGPR + ~64 VGPR -> 2 blocks/CU; LDS 64 KB (B 3-buf 48 + A dbuf 16).
// SINGLE CHANGE vs R16: per-period issue order [glA(ck+2), B(ck+2), writeA, storeO]
// (stores youngest) + phase-derived tail counts keep = 4 + 2*(st(ck) alive)
// + 2*(st(ck+1) issued) -> nt-store acks get ~2 periods of slack instead of 0.
// Role-split copy-out (each out element once); XCD pair-swizzle; nt dense stores.
__global__ __launch_bounds__(512, 4) void comp_gemm_kernel(
    const float* __restrict__ states,
    const unsigned short* __restrict__ wT,
    const float* __restrict__ cb1,
    const float* __restrict__ cW2,
    float* __restrict__ out,
    float* __restrict__ part_ws) {
    __shared__ alignas(16) char lds[65536];   // B [3][256][64] @0 ; A [2][128][64] @49152
    char* ldsB = lds;
    char* ldsA = lds + 49152;

    const int t = threadIdx.x;
    const int lane = t & 63;
    const int wv = t >> 6;                // 0..7
    const int wm = wv >> 2;               // 0..1 : rows [wm*64, +64)
    const int wn = wv & 3;                // 0..3 : cols [wn*64, +64)
    const int la = lane & 15;
    const int lg = lane >> 4;

    // XCD pair-swizzle: logical ids 2m,2m+1 <- physical bids m, m+8 (same XCD)
    const int bid = blockIdx.x;
    const int bidL = (bid & 7) * 128 + (bid >> 3);
    const int b = bidL >> 6;              // 16 b
    const int rem = bidL & 63;
    const int s0 = (rem >> 1) * 128;      // 32 s-tiles of 128
    const int nhalf = rem & 1;            // 2 N-halves
    const int n0 = nhalf * 256;

    // ---- A staging / fused copy-out: (row=t>>2, half=t&3); two f4 at +0/+64 B
    // -> per-instruction footprint = 16 rows x 64 B DENSE ----
    const int arow = t >> 2;
    const int half = t & 3;
    const size_t abase = ((size_t)b * S_LEN + s0 + arow) * H_DIM + half * 4;
    const float* srcA = states + abase;
    float* dstO = out + abase;
    const int ax = (arow & 3) ^ ((arow >> 2) & 3);
    char* dstA0 = ldsA + arow * 64 + (((half >> 1) ^ ax) * 16 + (half & 1) * 8);
    char* dstA1 = ldsA + arow * 64 + ((((half >> 1) + 2) ^ ax) * 16 + (half & 1) * 8);

    // ---- B staging: 2 x global_load_lds(16B/lane)/chunk; linear dest, swizzled src ----
    const char* srcB = (const char*)wT + (size_t)(n0 + (t >> 2)) * 2048 + (t & 3) * 16;
    char* dstB = ldsB + t * 16;

    // ---- fragment read bases (2-way bank, free) ----
    const char* brd = ldsB + (wn * 64 + la) * 64 + ((lg ^ ((la >> 1) & 3)) * 16);
    const char* ard = ldsA + (wm * 64 + la) * 64 + ((lg ^ (la & 3) ^ ((la >> 2) & 3)) * 16);

    f4 acc[4][4];
#pragma unroll
    for (int a = 0; a < 4; ++a)
#pragma unroll
        for (int c = 0; c < 4; ++c) acc[a][c] = f4{0.f, 0.f, 0.f, 0.f};

    auto issueB = [&](int bufi, int ck_) {
#pragma unroll
        for (int i = 0; i < 2; ++i)
            __builtin_amdgcn_global_load_lds((gvp)(srcB + (size_t)i * 128 * 2048 + ck_ * 64),
                                             (lvp)(dstB + bufi * 16384 + i * 8192), 16, 0, 0);
    };
    auto writeA = [&](int bufa, const f4 a0, const f4 a1) {
        bf4 p0, p1;
        p0[0] = (short)f2bf(a0.x); p0[1] = (short)f2bf(a0.y);
        p0[2] = (short)f2bf(a0.z); p0[3] = (short)f2bf(a0.w);
        p1[0] = (short)f2bf(a1.x); p1[1] = (short)f2bf(a1.y);
        p1[2] = (short)f2bf(a1.z); p1[3] = (short)f2bf(a1.w);
        *(bf4*)(dstA0 + bufa * 8192) = p0;
        *(bf4*)(dstA1 + bufa * 8192) = p1;
    };
    auto storeO = [&](int ck_, const f4 a0, const f4 a1) {    // nt, per-instr dense
        __builtin_nontemporal_store(a0, (f4*)(dstO + ck_ * 32));
        __builtin_nontemporal_store(a1, (f4*)(dstO + ck_ * 32 + 16));
    };

    // ---- prologue: [glA0, B0, writeA0 (waits glA0), st0?, glA1, B1] ----
    f4 qa0 = *(const f4*)(srcA);
    f4 qa1 = *(const f4*)(srcA + 16);
    issueB(0, 0);
    writeA(0, qa0, qa1);                 // qa-wait retires glA0 only; B0 younger survives
    if (nhalf == 0) storeO(0, qa0, qa1); // chunk 0 belongs to nhalf 0
    f4 qn0 = *(const f4*)(srcA + 32);
    f4 qn1 = *(const f4*)(srcA + 48);
    issueB(1, 1);
    // queue: [B0 x2, st0? x2, glA1 x2, B1 x2] -> retire B0, keep 2*st + 4
    if (nhalf == 0) { asm volatile("s_waitcnt vmcnt(6) lgkmcnt(0)" ::: "memory"); }
    else            { asm volatile("s_waitcnt vmcnt(4) lgkmcnt(0)" ::: "memory"); }
    __builtin_amdgcn_sched_barrier(0);
    __builtin_amdgcn_s_barrier();
    __builtin_amdgcn_sched_barrier(0);
    qa0 = qn0; qa1 = qn1;

#pragma unroll 1
    for (int ck = 0; ck < 32; ++ck) {
        const int bufc = ck % 3;
        if (ck < 31) {
            // issue order: glA first, B next, lds-write (qa-wait hits glA(ck+1) only),
            // nt-stores LAST (youngest -> survive the tail)
            if (ck < 30) {
                qn0 = *(const f4*)(srcA + (ck + 2) * 32);
                qn1 = *(const f4*)(srcA + (ck + 2) * 32 + 16);
                issueB((ck + 2) % 3, ck + 2);
            }
            writeA((ck + 1) & 1, qa0, qa1);
            if (((ck + 1) >> 4) == nhalf) storeO(ck + 1, qa0, qa1);   // role-split
            __builtin_amdgcn_sched_barrier(0);
        }
        // ---- compute chunk ck: A from ldsA[ck&1], B from buf[ck%3] ----
        bf8 af[4];
#pragma unroll
        for (int fr = 0; fr < 4; ++fr)
            af[fr] = *(const bf8*)(ard + (ck & 1) * 8192 + fr * 1024);
#pragma unroll
        for (int fc = 0; fc < 4; ++fc) {
            const bf8 bv = *(const bf8*)(brd + bufc * 16384 + fc * 1024);
#pragma unroll
            for (int fr = 0; fr < 4; ++fr)
                acc[fr][fc] = __builtin_amdgcn_mfma_f32_16x16x32_bf16(af[fr], bv, acc[fr][fc], 0, 0, 0);
        }
        if (ck < 31) {
            if (ck < 30) {
                // keep = 4 (glA,B(ck+2)) + 2 if st(ck) alive (ck>=1, issued p(ck-1),
                // younger than B(ck+1)) + 2 if st(ck+1) issued this period.
                const int keep = 4 + ((ck >= 1 && (ck >> 4) == nhalf) ? 2 : 0)
                                   + ((((ck + 1) >> 4) == nhalf) ? 2 : 0);
                if (keep == 8)      { asm volatile("s_waitcnt vmcnt(8) lgkmcnt(0)" ::: "memory"); }
                else if (keep == 6) { asm volatile("s_waitcnt vmcnt(6) lgkmcnt(0)" ::: "memory"); }
                else                { asm volatile("s_waitcnt vmcnt(4) lgkmcnt(0)" ::: "memory"); }
            } else {
                asm volatile("s_waitcnt vmcnt(0) lgkmcnt(0)" ::: "memory");   // one-time drain
            }
            __builtin_amdgcn_sched_barrier(0);
            __builtin_amdgcn_s_barrier();
            __builtin_amdgcn_sched_barrier(0);
            if (ck < 30) { qa0 = qn0; qa1 = qn1; }
        }
    }

    // ---- epilogue: relu + dot(cW2-half) -> raw half-logit per (b,s) ----
    float w2v[4], b1v[4];
#pragma unroll
    for (int fc = 0; fc < 4; ++fc) {
        const int d = n0 + wn * 64 + fc * 16 + la;
        w2v[fc] = cW2[d];
        b1v[fc] = cb1[d];
    }
    float* part = (float*)ldsA;   // [128 rows][4 wn] overlays A-buf0 (iter31 read A-buf1)
#pragma unroll
    for (int fr = 0; fr < 4; ++fr) {
#pragma unroll
        for (int rg = 0; rg < 4; ++rg) {
            float p = 0.f;
#pragma unroll
            for (int fc = 0; fc < 4; ++fc)
                p += fmaxf(acc[fr][fc][rg] + b1v[fc], 0.f) * w2v[fc];
#pragma unroll
            for (int off = 1; off < 16; off <<= 1)
                p += __shfl_xor(p, off, 64);      // sum over 16 lane-columns (n)
            if (la == 0) part[(wm * 64 + fr * 16 + lg * 4 + rg) * 4 + wn] = p;
        }
    }
    __syncthreads();
    if (t < 128) {
        const float sum = part[t * 4 + 0] + part[t * 4 + 1] + part[t * 4 + 2] + part[t * 4 + 3];
        __builtin_nontemporal_store(
            sum, part_ws + ((size_t)(nhalf * B_DIM + b)) * S_LEN + s0 + t);
    }
}

// comp_mean[s] = (1/16) sum_b sigmoid(cb2 + half0[b][s] + half1[b][s]);
// steps_used ≡ 1 (rb<=128-t can never make trunc(rb/(S-t+1))>=2; negative rb clips
// to 1); rb_final = 128-4096 = -3968.
__global__ __launch_bounds__(256) void reduce_comp(const float* __restrict__ part_ws,
                                                   const float* __restrict__ cb2,
                                                   float* __restrict__ out) {
    const int s = blockIdx.x * 256 + threadIdx.x;
    const float c2 = cb2[0];
    float sum = 0.f;
#pragma unroll
    for (int b = 0; b < B_DIM; ++b) {
        const float l = c2 + part_ws[(size_t)b * S_LEN + s]
                           + part_ws[((size_t)B_DIM + b) * S_LEN + s];
        sum += 1.f / (1.f + __expf(-l));
    }
    out[OUT_BASE + S_LEN + s] = sum * (1.f / 16.f);   // comp_mean
    out[OUT_BASE + s] = 1.0f;                          // steps_used
    if (s == 0) out[OUT_BASE + 2 * S_LEN] = -3968.0f;  // rb_final.mean()
}

extern "C" void kernel_launch(void* const* d_in, const int* in_sizes, int n_in,
                              void* d_out, int out_size, void* d_ws, size_t ws_size,
                              hipStream_t stream) {
    const float* states = (const float*)d_in[0];
    const float* cW1 = (const float*)d_in[5];
    const float* cb1 = (const float*)d_in[6];
    const float* cW2 = (const float*)d_in[7];
    const float* cb2 = (const float*)d_in[8];
    float* out = (float*)d_out;
    unsigned short* wT = (unsigned short*)d_ws;                 // 1 MB bf16, pre-swizzled
    float* part_ws = (float*)((char*)d_ws + (size_t)D_DIM * H_DIM * 2);  // 512 KB [2][16][4096]

    hipLaunchKernelGGL(prep_transpose, dim3(128), dim3(256), 0, stream, cW1, wT);
    hipLaunchKernelGGL(comp_gemm_kernel, dim3(1024), dim3(512), 0, stream,
                       states, wT, cb1, cW2, out, part_ws);
    hipLaunchKernelGGL(reduce_comp, dim3(16), dim3(256), 0, stream, part_ws, cb2, out);
}